// Round 1
// baseline (866.294 us; speedup 1.0000x reference)
//
#include <hip/hip_runtime.h>
#include <hip/hip_fp16.h>

#define Nn 50000
#define Ee 800000
#define Tt 12
#define NBAND 8
#define BAND 6250        // Nn / NBAND exactly
#define SCB 196          // scan blocks per half: 196*256 >= Nn
// HID=128, K=3, F_IN=7, effective features = 35 (+1 bias slot)
// Node feature rows: 8 x f16 = 16 B (one dwordx4 gather).
// Packed edge record (8 B): {lo = (c<<16)|wb, hi = (r<<16)|wb}, wb = f16(w).
// adjR entry = lo (keyed by r), adjC entry = hi (keyed by c).

// ============ pack edges + degree histogram (one pass over edges) ==========
// ei/ew are single-use streams -> nontemporal loads; packed is only ever
// consumed via nt reads in scatter -> nt store (keep it out of L2).
__global__ __launch_bounds__(256) void pack_hist_kernel(
    const int* __restrict__ ei, const float* __restrict__ ew,
    uint2* __restrict__ packed, int* __restrict__ cntR, int* __restrict__ cntC)
{
    int e = blockIdx.x * 256 + threadIdx.x;
    if (e >= Ee) return;
    int r = __builtin_nontemporal_load(ei + e);
    int c = __builtin_nontemporal_load(ei + Ee + e);
    float w = __builtin_nontemporal_load(ew + e);
    unsigned wb = __half_as_ushort(__float2half(w));
    unsigned lo = ((unsigned)c << 16) | wb;
    unsigned hi = ((unsigned)r << 16) | wb;
    unsigned long long v = ((unsigned long long)hi << 32) | lo;
    __builtin_nontemporal_store(v, (unsigned long long*)packed + e);
    atomicAdd(&cntR[r], 1);
    atomicAdd(&cntC[c], 1);
}

// ---- 3-phase multi-block exclusive scan of cntR / cntC --------------------
__global__ __launch_bounds__(256) void scanA_kernel(
    const int* __restrict__ cntR, const int* __restrict__ cntC,
    int* __restrict__ bsum)
{
    const int* cnt = blockIdx.y ? cntC : cntR;
    int i = blockIdx.x * 256 + threadIdx.x;
    int v = (i < Nn) ? cnt[i] : 0;
    __shared__ int ws_[4];
    v += __shfl_xor(v, 1);  v += __shfl_xor(v, 2);  v += __shfl_xor(v, 4);
    v += __shfl_xor(v, 8);  v += __shfl_xor(v, 16); v += __shfl_xor(v, 32);
    if ((threadIdx.x & 63) == 0) ws_[threadIdx.x >> 6] = v;
    __syncthreads();
    if (threadIdx.x == 0)
        bsum[blockIdx.y * 256 + blockIdx.x] = ws_[0] + ws_[1] + ws_[2] + ws_[3];
}

__global__ __launch_bounds__(256) void scanB_kernel(
    const int* __restrict__ bsum, int* __restrict__ bbase)
{
    int y = blockIdx.x;
    __shared__ int s[256];
    int t = threadIdx.x;
    int v = (t < SCB) ? bsum[y * 256 + t] : 0;
    s[t] = v;
    __syncthreads();
    for (int off = 1; off < 256; off <<= 1) {
        int u = (t >= off) ? s[t - off] : 0;
        __syncthreads();
        s[t] += u;
        __syncthreads();
    }
    bbase[y * 256 + t] = s[t] - v;   // exclusive
}

__global__ __launch_bounds__(256) void scanC_kernel(
    const int* __restrict__ cntR, const int* __restrict__ cntC,
    const int* __restrict__ bbase,
    int* __restrict__ startR, int* __restrict__ startC,
    int* __restrict__ nextR, int* __restrict__ nextC)
{
    int y = blockIdx.y;
    const int* cnt = y ? cntC : cntR;
    int* start     = y ? startC : startR;
    int* nxt       = y ? nextC : nextR;
    int i = blockIdx.x * 256 + threadIdx.x;
    int v = (i < Nn) ? cnt[i] : 0;
    __shared__ int s[256];
    int t = threadIdx.x;
    s[t] = v;
    __syncthreads();
    for (int off = 1; off < 256; off <<= 1) {
        int u = (t >= off) ? s[t - off] : 0;
        __syncthreads();
        s[t] += u;
        __syncthreads();
    }
    int st = bbase[y * 256 + blockIdx.x] + s[t] - v;
    if (i < Nn) { start[i] = st; nxt[i] = st; }
}

// Banded scatter: block handles destination band (blockIdx & 7); with the
// blockIdx%8 -> XCD round-robin each band's write region stays L2-hot.
// packed reads are NONTEMPORAL (don't evict the adj write lines from L2)
// and 4-deep unrolled so LLC-latency reads stay pipelined.
__global__ __launch_bounds__(256) void scatter_banded(
    const uint2* __restrict__ packed,
    int* __restrict__ nextR, int* __restrict__ nextC,
    unsigned* __restrict__ adjR, unsigned* __restrict__ adjC)
{
    int band = blockIdx.x & (NBAND - 1);
    int chunk = blockIdx.x >> 3;
    int blo = band * BAND, bhi = blo + BAND;
    int stride = (gridDim.x >> 3) * 256;
    const unsigned long long* p64 = (const unsigned long long*)packed;
    for (int e0 = chunk * 256 + threadIdx.x; e0 < Ee; e0 += 4 * stride) {
        int e1 = e0 + stride, e2 = e0 + 2 * stride, e3 = e0 + 3 * stride;
        bool g1 = e1 < Ee, g2 = e2 < Ee, g3 = e3 < Ee;
        unsigned long long p0 = __builtin_nontemporal_load(p64 + e0);
        unsigned long long p1 = __builtin_nontemporal_load(p64 + (g1 ? e1 : e0));
        unsigned long long p2 = __builtin_nontemporal_load(p64 + (g2 ? e2 : e0));
        unsigned long long p3 = __builtin_nontemporal_load(p64 + (g3 ? e3 : e0));
        #define PROC(p, ok) do { if (ok) {                                     \
            unsigned lo = (unsigned)(p); unsigned hi = (unsigned)((p) >> 32);  \
            int c = (int)(lo >> 16), r = (int)(hi >> 16);                      \
            if (r >= blo && r < bhi) adjR[atomicAdd(&nextR[r], 1)] = lo;       \
            if (c >= blo && c < bhi) adjC[atomicAdd(&nextC[c], 1)] = hi;       \
        } } while (0)
        PROC(p0, true); PROC(p1, g1); PROC(p2, g2); PROC(p3, g3);
        #undef PROC
    }
}

// ==== effective weights, layout [gate][k*128 + j], k=35 is the bias row ====
// f layout: [0..6]=X, [7..13]=Tx_o, [14..20]=Tx_i, [21..27]=T2_o, [28..34]=T2_i, [35]=1
__global__ __launch_bounds__(256) void weff_kernel(
    const float* __restrict__ Wz, const float* __restrict__ Wh,
    const float* __restrict__ bz, const float* __restrict__ bh,
    float* __restrict__ wzT, float* __restrict__ whT)
{
    int idx = blockIdx.x * 256 + threadIdx.x;
    if (idx >= 2 * 36 * 128) return;
    const float* W = (idx < 36 * 128) ? Wz : Wh;
    const float* B = (idx < 36 * 128) ? bz : bh;
    float* O       = (idx < 36 * 128) ? wzT : whT;
    int rem = idx % (36 * 128);
    int k = rem / 128, j = rem % 128;
    float v;
    if (k == 35) v = B[j];
    else {
        int p = k / 7, rr = k % 7;
        // W flat: ((d*3 + kk)*135 + rr)*128 + j
        if (p == 0)      v = W[(0 * 135 + rr) * 128 + j] + W[(3 * 135 + rr) * 128 + j];
        else if (p == 1) v = W[(1 * 135 + rr) * 128 + j];
        else if (p == 2) v = W[(4 * 135 + rr) * 128 + j];
        else if (p == 3) v = W[(2 * 135 + rr) * 128 + j];
        else             v = W[(5 * 135 + rr) * 128 + j];
    }
    O[k * 128 + j] = v;
}

// =================== init: Xh row (f16) and out column 0 ===================
__global__ __launch_bounds__(256) void init_kernel(
    const float* __restrict__ x, const float* __restrict__ env,
    const float* __restrict__ coords, __half* __restrict__ Xh,
    float* __restrict__ out)
{
    int i = blockIdx.x * 256 + threadIdx.x;
    if (i >= Nn) return;
    float xv = x[i * Tt];
    __half* r = Xh + (long)i * 8;
    r[0] = __float2half(xv);
    #pragma unroll
    for (int c = 0; c < 4; c++) r[1 + c] = __float2half(env[i * 48 + c * 12]);
    r[5] = __float2half(coords[i * 2 + 0]);
    r[6] = __float2half(coords[i * 2 + 1]);
    r[7] = __half(0.f);
    out[i * 13 + 0] = xv;
}

__device__ __forceinline__ void unpack8(const __half* p, float* v) {
    uint4 hv = *((const uint4*)p);
    float2 p0 = __half22float2(*(__half2*)&hv.x);
    float2 p1 = __half22float2(*(__half2*)&hv.y);
    float2 p2 = __half22float2(*(__half2*)&hv.z);
    float2 p3 = __half22float2(*(__half2*)&hv.w);
    v[0] = p0.x; v[1] = p0.y; v[2] = p1.x; v[3] = p1.y;
    v[4] = p2.x; v[5] = p2.y; v[6] = p3.x;
}

__device__ __forceinline__ void pack8(__half* p, const float* v) {
    __half2 q0 = __floats2half2_rn(v[0], v[1]);
    __half2 q1 = __floats2half2_rn(v[2], v[3]);
    __half2 q2 = __floats2half2_rn(v[4], v[5]);
    __half2 q3 = __floats2half2_rn(v[6], 0.f);
    uint4 st;
    st.x = *(unsigned*)&q0; st.y = *(unsigned*)&q1;
    st.z = *(unsigned*)&q2; st.w = *(unsigned*)&q3;
    *((uint4*)p) = st;
}

// accumulate a[0..6] += w * halfrow(hv)
__device__ __forceinline__ void acc7(float* a, float w, uint4 hv) {
    float2 p0 = __half22float2(*(__half2*)&hv.x);
    float2 p1 = __half22float2(*(__half2*)&hv.y);
    float2 p2 = __half22float2(*(__half2*)&hv.z);
    float2 p3 = __half22float2(*(__half2*)&hv.w);
    a[0] = fmaf(w, p0.x, a[0]); a[1] = fmaf(w, p0.y, a[1]);
    a[2] = fmaf(w, p1.x, a[2]); a[3] = fmaf(w, p1.y, a[3]);
    a[4] = fmaf(w, p2.x, a[4]); a[5] = fmaf(w, p2.y, a[5]);
    a[6] = fmaf(w, p3.x, a[6]);
}

__device__ __forceinline__ float wdec(unsigned ed) {
    return __half2float(__ushort_as_half((unsigned short)(ed & 0xffffu)));
}

// ============== gather pass 1: Tx = inv * segsum(w * Xh[src]) ==============
// 16 threads per node: bit3 = dir (out/in), bits0-2 = sub (8 lanes/dir).
// Branchless fixed-depth issue: 3 clamped adj loads + 3 row gathers, all in
// flight before one wait (covers deg<=24; Poisson(16) tail ~2% takes the
// fallback loop). Invalid slots clamp to entry b with weight 0 -> duplicate
// addresses coalesce within the wave.
__global__ __launch_bounds__(256) void gather1_kernel(
    const int* __restrict__ startR, const int* __restrict__ cntR,
    const unsigned* __restrict__ adjR,
    const int* __restrict__ startC, const int* __restrict__ cntC,
    const unsigned* __restrict__ adjC,
    const __half* __restrict__ Xh,
    __half* __restrict__ TxoH, __half* __restrict__ TxiH,
    float* __restrict__ inv_out, float* __restrict__ inv_in)
{
    int tid = blockIdx.x * 256 + threadIdx.x;   // grid is exactly Nn*16 threads
    int node = tid >> 4;
    int dir = (tid >> 3) & 1, sub = tid & 7;
    const int*      st  = dir ? startC : startR;
    const int*      cn  = dir ? cntC : cntR;
    const unsigned* adj = dir ? adjC : adjR;
    int b = st[node], e = b + cn[node];
    int safe = (b < e) ? b : 0;
    int k0 = b + sub;
    bool v0 = k0 < e, v1 = k0 + 8 < e, v2 = k0 + 16 < e;
    unsigned e0 = adj[v0 ? k0 : safe];
    unsigned e1 = adj[v1 ? k0 + 8 : safe];
    unsigned e2 = adj[v2 ? k0 + 16 : safe];
    uint4 r0 = *(const uint4*)(Xh + (long)(e0 >> 16) * 8);
    uint4 r1 = *(const uint4*)(Xh + (long)(e1 >> 16) * 8);
    uint4 r2 = *(const uint4*)(Xh + (long)(e2 >> 16) * 8);
    float w0 = v0 ? wdec(e0) : 0.f;
    float w1 = v1 ? wdec(e1) : 0.f;
    float w2 = v2 ? wdec(e2) : 0.f;
    float a[7] = {0.f, 0.f, 0.f, 0.f, 0.f, 0.f, 0.f};
    acc7(a, w0, r0); acc7(a, w1, r1); acc7(a, w2, r2);
    float sw = (w0 + w1) + w2;
    for (int k = k0 + 24; k < e; k += 8) {       // rare (deg > 24)
        unsigned ed = adj[k];
        uint4 rv = *(const uint4*)(Xh + (long)(ed >> 16) * 8);
        float w = wdec(ed);
        acc7(a, w, rv);
        sw += w;
    }
    #pragma unroll
    for (int m = 1; m <= 4; m <<= 1) {
        #pragma unroll
        for (int q = 0; q < 7; q++) a[q] += __shfl_xor(a[q], m);
        sw += __shfl_xor(sw, m);
    }
    if (sub == 0) {
        float inv = sw > 0.f ? 1.f / sw : 0.f;
        (dir ? inv_in : inv_out)[node] = inv;
        #pragma unroll
        for (int q = 0; q < 7; q++) a[q] *= inv;
        pack8((dir ? TxiH : TxoH) + (long)node * 8, a);
    }
}

// ====== fused step2: second-order propagation (into LDS, fp32) + dense =====
// Block = 512 threads = 32 nodes.
// Phase A: 16 threads/node (dir = bit3, sub = bits0-2), same branchless
// fixed-depth issue as gather1; T2, Tx, X -> f_s.
// Phase B: channel-resident weights (72 VGPR/lane); wave w: channels
// (w&1)*64..+64 for node quarter (w>>1)*8..+8; pure register FMA inner loop.
__global__ __launch_bounds__(512) void step2_kernel(
    const int* __restrict__ startR, const int* __restrict__ cntR,
    const unsigned* __restrict__ adjR,
    const int* __restrict__ startC, const int* __restrict__ cntC,
    const unsigned* __restrict__ adjC,
    const float* __restrict__ inv_out, const float* __restrict__ inv_in,
    const float* __restrict__ env, const float* __restrict__ night,
    const float* __restrict__ wzT, const float* __restrict__ whT,
    const float* __restrict__ linW, const float* __restrict__ linb,
    __half* __restrict__ Xh,
    const __half* __restrict__ TxoH, const __half* __restrict__ TxiH,
    float* __restrict__ out, int t)
{
    __shared__ float f_s[32][36];
    __shared__ float part_s[2][32];
    int tid = threadIdx.x;
    int base = blockIdx.x * 32;

    // ---- phase A: T2 for this block's 32 nodes, straight into LDS ----
    {
        int nl = tid >> 4;                 // 0..31
        int dir = (tid >> 3) & 1, sub = tid & 7;
        int node = base + nl;
        int nc = node < Nn ? node : Nn - 1;   // clamp; output stores guarded
        const int*      st  = dir ? startC : startR;
        const int*      cn  = dir ? cntC : cntR;
        const unsigned* adj = dir ? adjC : adjR;
        const __half*   src = dir ? TxiH : TxoH;
        int b = st[nc], e = b + cn[nc];
        int safe = (b < e) ? b : 0;
        int k0 = b + sub;
        bool v0 = k0 < e, v1 = k0 + 8 < e, v2 = k0 + 16 < e;
        unsigned e0 = adj[v0 ? k0 : safe];
        unsigned e1 = adj[v1 ? k0 + 8 : safe];
        unsigned e2 = adj[v2 ? k0 + 16 : safe];
        uint4 r0 = *(const uint4*)(src + (long)(e0 >> 16) * 8);
        uint4 r1 = *(const uint4*)(src + (long)(e1 >> 16) * 8);
        uint4 r2 = *(const uint4*)(src + (long)(e2 >> 16) * 8);
        float w0 = v0 ? wdec(e0) : 0.f;
        float w1 = v1 ? wdec(e1) : 0.f;
        float w2 = v2 ? wdec(e2) : 0.f;
        float a[7] = {0.f, 0.f, 0.f, 0.f, 0.f, 0.f, 0.f};
        acc7(a, w0, r0); acc7(a, w1, r1); acc7(a, w2, r2);
        for (int k = k0 + 24; k < e; k += 8) {   // rare (deg > 24)
            unsigned ed = adj[k];
            uint4 rv = *(const uint4*)(src + (long)(ed >> 16) * 8);
            acc7(a, wdec(ed), rv);
        }
        #pragma unroll
        for (int m = 1; m <= 4; m <<= 1) {
            #pragma unroll
            for (int q = 0; q < 7; q++) a[q] += __shfl_xor(a[q], m);
        }
        if (sub == 0) {
            float s2 = 2.f * (dir ? inv_in[nc] : inv_out[nc]);
            float xv[7], tx[7];
            unpack8(Xh + (long)nc * 8, xv);
            unpack8(src + (long)nc * 8, tx);     // own Tx row (dir-matched)
            #pragma unroll
            for (int q = 0; q < 7; q++) {
                f_s[nl][21 + 7 * dir + q] = fmaf(s2, a[q], -xv[q]);
                f_s[nl][7 + 7 * dir + q]  = tx[q];
            }
            if (dir == 0) {
                #pragma unroll
                for (int q = 0; q < 7; q++) f_s[nl][q] = xv[q];
                f_s[nl][35] = 1.f;
            }
        }
    }
    __syncthreads();

    // ---- phase B: dense 36x128x2 contraction + activations + output ----
    int lane = tid & 63;
    int wave = tid >> 6;          // 0..7
    int chSel = wave & 1;
    int ch = chSel * 64 + lane;
    int q8 = wave >> 1;           // node quarter
    float wz[36], wh[36];
    #pragma unroll
    for (int k = 0; k < 36; k++) wz[k] = wzT[k * 128 + ch];
    #pragma unroll
    for (int k = 0; k < 36; k++) wh[k] = whT[k * 128 + ch];
    float lw = linW[ch];
    float lb = linb[0];

    #pragma unroll 1
    for (int n = 0; n < 8; n++) {
        int ni = q8 * 8 + n;
        const float4* fv = (const float4*)f_s[ni];   // broadcast reads
        float hz = 0.f, hh = 0.f;
        #pragma unroll
        for (int q = 0; q < 9; q++) {
            float4 fq = fv[q];
            hz = fmaf(fq.x, wz[q*4+0], hz); hh = fmaf(fq.x, wh[q*4+0], hh);
            hz = fmaf(fq.y, wz[q*4+1], hz); hh = fmaf(fq.y, wh[q*4+1], hh);
            hz = fmaf(fq.z, wz[q*4+2], hz); hh = fmaf(fq.z, wh[q*4+2], hh);
            hz = fmaf(fq.w, wz[q*4+3], hz); hh = fmaf(fq.w, wh[q*4+3], hh);
        }
        float z  = 1.f / (1.f + __expf(-hz));
        float e2 = __expf(2.f * hh);
        float ht = 1.f - 2.f / (e2 + 1.f);           // tanh
        float v = fmaxf((1.f - z) * ht, 0.f) * lw;   // (1-Z)*H~, relu, lin
        v += __shfl_xor(v, 1);  v += __shfl_xor(v, 2);  v += __shfl_xor(v, 4);
        v += __shfl_xor(v, 8);  v += __shfl_xor(v, 16); v += __shfl_xor(v, 32);
        if (lane == 0) part_s[chSel][ni] = v;
    }
    __syncthreads();
    if (tid < 32) {
        int node = base + tid;
        if (node < Nn) {
            float o = part_s[0][tid] + part_s[1][tid] + lb;
            o *= night[(long)node * 13 + t + 1];
            out[(long)node * 13 + t + 1] = o;
            if (t + 1 < Tt) {
                __half* xr = Xh + (long)node * 8;
                xr[0] = __float2half(o);
                #pragma unroll
                for (int c = 0; c < 4; c++)
                    xr[1 + c] = __float2half(env[(long)node * 48 + c * 12 + t + 1]);
            }
        }
    }
}

extern "C" void kernel_launch(void* const* d_in, const int* in_sizes, int n_in,
                              void* d_out, int out_size, void* d_ws, size_t ws_size,
                              hipStream_t stream) {
    const float* x      = (const float*)d_in[0];
    const float* env    = (const float*)d_in[1];
    const float* coords = (const float*)d_in[2];
    const int*   ei     = (const int*)d_in[3];
    const float* ew     = (const float*)d_in[4];
    const float* night  = (const float*)d_in[5];
    const float* Wz     = (const float*)d_in[6];
    const float* bz     = (const float*)d_in[7];
    // d_in[8]=Wr, d_in[9]=br unused (R gate never affects output)
    const float* Wh     = (const float*)d_in[10];
    const float* bh     = (const float*)d_in[11];
    const float* linW   = (const float*)d_in[12];
    const float* linb   = (const float*)d_in[13];
    float* out = (float*)d_out;

    float* w = (float*)d_ws;
    float* wzT     = w;                     // 36*128
    float* whT     = w + 4608;
    float* inv_out = w + 9216;              // N
    float* inv_in  = w + 59216;
    __half* Xh   = (__half*)(w + 109216);   // N x 8 halves (16B-aligned offsets)
    __half* TxoH = (__half*)(w + 309216);
    __half* TxiH = (__half*)(w + 509216);
    int* cntR    = (int*)(w + 709216);      // N
    int* cntC    = cntR + 50000;
    int* startR  = cntC + 50000;            // N
    int* startC  = startR + 50000;
    int* nextR   = startC + 50000;          // N
    int* nextC   = nextR + 50000;
    int* bsum    = nextC + 50000;           // 2 x 256
    int* bbase   = bsum + 512;              // 2 x 256
    uint2* packed  = (uint2*)(bbase + 512); // E x 8B (offset even -> 8B aligned)
    unsigned* adjR = (unsigned*)(packed + Ee);   // E x 4B
    unsigned* adjC = adjR + Ee;

    // ---- CSR build (per launch; ws is re-poisoned every call) ----
    hipMemsetAsync(cntR, 0, 2 * Nn * sizeof(int), stream);
    pack_hist_kernel<<<(Ee + 255) / 256, 256, 0, stream>>>(ei, ew, packed, cntR, cntC);
    scanA_kernel<<<dim3(SCB, 2), 256, 0, stream>>>(cntR, cntC, bsum);
    scanB_kernel<<<2, 256, 0, stream>>>(bsum, bbase);
    scanC_kernel<<<dim3(SCB, 2), 256, 0, stream>>>(
        cntR, cntC, bbase, startR, startC, nextR, nextC);
    scatter_banded<<<8 * 256, 256, 0, stream>>>(packed, nextR, nextC, adjR, adjC);

    weff_kernel<<<(2 * 36 * 128 + 255) / 256, 256, 0, stream>>>(Wz, Wh, bz, bh, wzT, whT);
    init_kernel<<<(Nn + 255) / 256, 256, 0, stream>>>(x, env, coords, Xh, out);

    for (int t = 0; t < Tt; t++) {
        gather1_kernel<<<(Nn * 16) / 256, 256, 0, stream>>>(
            startR, cntR, adjR, startC, cntC, adjC, Xh, TxoH, TxiH, inv_out, inv_in);
        step2_kernel<<<(Nn + 31) / 32, 512, 0, stream>>>(
            startR, cntR, adjR, startC, cntC, adjC, inv_out, inv_in,
            env, night, wzT, whT, linW, linb, Xh, TxoH, TxiH, out, t);
    }
}

// Round 2
// 826.859 us; speedup vs baseline: 1.0477x; 1.0477x over previous
//
#include <hip/hip_runtime.h>
#include <hip/hip_fp16.h>

#define Nn 50000
#define Ee 800000
#define Tt 12
#define NBAND 8
#define BAND 6250        // Nn / NBAND exactly
#define SCB 196          // scan blocks per half: 196*256 >= Nn
// HID=128, K=3, F_IN=7, effective features = 35 (+1 bias slot)
// Node feature rows: 8 x f16 = 16 B (one dwordx4 gather).
// Packed edge record (8 B): {lo = (c<<16)|wb, hi = (r<<16)|wb}, wb = f16(w).
// adjR entry = lo (keyed by r), adjC entry = hi (keyed by c).

// ============ pack edges + degree histogram (one pass over edges) ==========
__global__ __launch_bounds__(256) void pack_hist_kernel(
    const int* __restrict__ ei, const float* __restrict__ ew,
    uint2* __restrict__ packed, int* __restrict__ cntR, int* __restrict__ cntC)
{
    int e = blockIdx.x * 256 + threadIdx.x;
    if (e >= Ee) return;
    int r = ei[e], c = ei[Ee + e];
    unsigned wb = __half_as_ushort(__float2half(ew[e]));
    packed[e] = make_uint2(((unsigned)c << 16) | wb, ((unsigned)r << 16) | wb);
    atomicAdd(&cntR[r], 1);
    atomicAdd(&cntC[c], 1);
}

// ---- 3-phase multi-block exclusive scan of cntR / cntC --------------------
__global__ __launch_bounds__(256) void scanA_kernel(
    const int* __restrict__ cntR, const int* __restrict__ cntC,
    int* __restrict__ bsum)
{
    const int* cnt = blockIdx.y ? cntC : cntR;
    int i = blockIdx.x * 256 + threadIdx.x;
    int v = (i < Nn) ? cnt[i] : 0;
    __shared__ int ws_[4];
    v += __shfl_xor(v, 1);  v += __shfl_xor(v, 2);  v += __shfl_xor(v, 4);
    v += __shfl_xor(v, 8);  v += __shfl_xor(v, 16); v += __shfl_xor(v, 32);
    if ((threadIdx.x & 63) == 0) ws_[threadIdx.x >> 6] = v;
    __syncthreads();
    if (threadIdx.x == 0)
        bsum[blockIdx.y * 256 + blockIdx.x] = ws_[0] + ws_[1] + ws_[2] + ws_[3];
}

__global__ __launch_bounds__(256) void scanB_kernel(
    const int* __restrict__ bsum, int* __restrict__ bbase)
{
    int y = blockIdx.x;
    __shared__ int s[256];
    int t = threadIdx.x;
    int v = (t < SCB) ? bsum[y * 256 + t] : 0;
    s[t] = v;
    __syncthreads();
    for (int off = 1; off < 256; off <<= 1) {
        int u = (t >= off) ? s[t - off] : 0;
        __syncthreads();
        s[t] += u;
        __syncthreads();
    }
    bbase[y * 256 + t] = s[t] - v;   // exclusive
}

__global__ __launch_bounds__(256) void scanC_kernel(
    const int* __restrict__ cntR, const int* __restrict__ cntC,
    const int* __restrict__ bbase,
    int* __restrict__ startR, int* __restrict__ startC,
    int* __restrict__ nextR, int* __restrict__ nextC,
    int* __restrict__ bandCurR, int* __restrict__ bandCurC)
{
    int y = blockIdx.y;
    const int* cnt = y ? cntC : cntR;
    int* start     = y ? startC : startR;
    int* nxt       = y ? nextC : nextR;
    int i = blockIdx.x * 256 + threadIdx.x;
    int v = (i < Nn) ? cnt[i] : 0;
    __shared__ int s[256];
    int t = threadIdx.x;
    s[t] = v;
    __syncthreads();
    for (int off = 1; off < 256; off <<= 1) {
        int u = (t >= off) ? s[t - off] : 0;
        __syncthreads();
        s[t] += u;
        __syncthreads();
    }
    int st = bbase[y * 256 + blockIdx.x] + s[t] - v;
    if (i < Nn) {
        start[i] = st; nxt[i] = st;
        // band cursor init for two-pass scatter: base of band = CSR prefix
        if ((i % BAND) == 0) (y ? bandCurC : bandCurR)[i / BAND] = st;
    }
}

// ---------------- old single-pass banded scatter (fallback) ----------------
__global__ __launch_bounds__(256) void scatter_banded(
    const uint2* __restrict__ packed,
    int* __restrict__ nextR, int* __restrict__ nextC,
    unsigned* __restrict__ adjR, unsigned* __restrict__ adjC)
{
    int band = blockIdx.x & (NBAND - 1);
    int chunk = blockIdx.x >> 3;
    int lo = band * BAND, hi = lo + BAND;
    int stride = (gridDim.x >> 3) * 256;
    for (int e = chunk * 256 + threadIdx.x; e < Ee; e += stride) {
        uint2 p = packed[e];
        int c = (int)(p.x >> 16);
        int r = (int)(p.y >> 16);
        if (r >= lo && r < hi) adjR[atomicAdd(&nextR[r], 1)] = p.x;
        if (c >= lo && c < hi) adjC[atomicAdd(&nextC[c], 1)] = p.y;
    }
}

// -------- two-pass scatter, pass A: bucket records by destination band -----
// Block-aggregated: LDS rank per band -> one global cursor atomicAdd per band
// per block -> each block writes contiguous runs into bucketR/bucketC.
// Writes are run-contiguous so L2 lines fill completely before writeback.
__global__ __launch_bounds__(256) void bucketA_kernel(
    const uint2* __restrict__ packed,
    int* __restrict__ bandCurR, int* __restrict__ bandCurC,
    uint2* __restrict__ bucketR, uint2* __restrict__ bucketC)
{
    __shared__ int cnt_s[16];    // [0..7]=R bands, [8..15]=C bands
    __shared__ int base_s[16];
    int t = threadIdx.x;
    for (int b0 = blockIdx.x * 256; b0 < Ee; b0 += gridDim.x * 256) {
        int e = b0 + t;
        bool ok = e < Ee;
        uint2 p = ok ? packed[e] : make_uint2(0u, 0u);
        int r = (int)(p.y >> 16), c = (int)(p.x >> 16);
        int bR = r / BAND, bC = c / BAND;
        if (t < 16) cnt_s[t] = 0;
        __syncthreads();
        int rkR = 0, rkC = 0;
        if (ok) {
            rkR = atomicAdd(&cnt_s[bR], 1);
            rkC = atomicAdd(&cnt_s[8 + bC], 1);
        }
        __syncthreads();
        if (t < 8)        base_s[t] = atomicAdd(&bandCurR[t], cnt_s[t]);
        else if (t < 16)  base_s[t] = atomicAdd(&bandCurC[t - 8], cnt_s[t]);
        __syncthreads();
        if (ok) {
            bucketR[base_s[bR] + rkR]     = p;
            bucketC[base_s[8 + bC] + rkC] = p;
        }
        __syncthreads();   // cnt_s reuse next iteration
    }
}

// -------- two-pass scatter, pass B: fine scatter within one band -----------
// blockIdx&7 = band -> XCD round-robin pins each band to one XCD; that XCD
// streams only its own ~1.6 MB bucket while its ~0.8 MB adj write region
// stays L2-resident, so dirty lines fill before writeback.
__global__ __launch_bounds__(256) void scatterB_kernel(
    const uint2* __restrict__ bucketR, const uint2* __restrict__ bucketC,
    const int* __restrict__ startR, const int* __restrict__ startC,
    int* __restrict__ nextR, int* __restrict__ nextC,
    unsigned* __restrict__ adjR, unsigned* __restrict__ adjC)
{
    int band = blockIdx.x & (NBAND - 1);
    int chunk = blockIdx.x >> 3;
    int stride = (gridDim.x >> 3) * 256;
    int sR = startR[band * BAND];
    int eR = (band < NBAND - 1) ? startR[(band + 1) * BAND] : Ee;
    for (int k = sR + chunk * 256 + threadIdx.x; k < eR; k += stride) {
        uint2 p = bucketR[k];
        int r = (int)(p.y >> 16);
        adjR[atomicAdd(&nextR[r], 1)] = p.x;
    }
    int sC = startC[band * BAND];
    int eC = (band < NBAND - 1) ? startC[(band + 1) * BAND] : Ee;
    for (int k = sC + chunk * 256 + threadIdx.x; k < eC; k += stride) {
        uint2 p = bucketC[k];
        int c = (int)(p.x >> 16);
        adjC[atomicAdd(&nextC[c], 1)] = p.y;
    }
}

// ==== effective weights, layout [gate][k*128 + j], k=35 is the bias row ====
// f layout: [0..6]=X, [7..13]=Tx_o, [14..20]=Tx_i, [21..27]=T2_o, [28..34]=T2_i, [35]=1
__global__ __launch_bounds__(256) void weff_kernel(
    const float* __restrict__ Wz, const float* __restrict__ Wh,
    const float* __restrict__ bz, const float* __restrict__ bh,
    float* __restrict__ wzT, float* __restrict__ whT)
{
    int idx = blockIdx.x * 256 + threadIdx.x;
    if (idx >= 2 * 36 * 128) return;
    const float* W = (idx < 36 * 128) ? Wz : Wh;
    const float* B = (idx < 36 * 128) ? bz : bh;
    float* O       = (idx < 36 * 128) ? wzT : whT;
    int rem = idx % (36 * 128);
    int k = rem / 128, j = rem % 128;
    float v;
    if (k == 35) v = B[j];
    else {
        int p = k / 7, rr = k % 7;
        // W flat: ((d*3 + kk)*135 + rr)*128 + j
        if (p == 0)      v = W[(0 * 135 + rr) * 128 + j] + W[(3 * 135 + rr) * 128 + j];
        else if (p == 1) v = W[(1 * 135 + rr) * 128 + j];
        else if (p == 2) v = W[(4 * 135 + rr) * 128 + j];
        else if (p == 3) v = W[(2 * 135 + rr) * 128 + j];
        else             v = W[(5 * 135 + rr) * 128 + j];
    }
    O[k * 128 + j] = v;
}

// =================== init: Xh row (f16) and out column 0 ===================
__global__ __launch_bounds__(256) void init_kernel(
    const float* __restrict__ x, const float* __restrict__ env,
    const float* __restrict__ coords, __half* __restrict__ Xh,
    float* __restrict__ out)
{
    int i = blockIdx.x * 256 + threadIdx.x;
    if (i >= Nn) return;
    float xv = x[i * Tt];
    __half* r = Xh + (long)i * 8;
    r[0] = __float2half(xv);
    #pragma unroll
    for (int c = 0; c < 4; c++) r[1 + c] = __float2half(env[i * 48 + c * 12]);
    r[5] = __float2half(coords[i * 2 + 0]);
    r[6] = __float2half(coords[i * 2 + 1]);
    r[7] = __half(0.f);
    out[i * 13 + 0] = xv;
}

__device__ __forceinline__ void unpack8(const __half* p, float* v) {
    uint4 hv = *((const uint4*)p);
    float2 p0 = __half22float2(*(__half2*)&hv.x);
    float2 p1 = __half22float2(*(__half2*)&hv.y);
    float2 p2 = __half22float2(*(__half2*)&hv.z);
    float2 p3 = __half22float2(*(__half2*)&hv.w);
    v[0] = p0.x; v[1] = p0.y; v[2] = p1.x; v[3] = p1.y;
    v[4] = p2.x; v[5] = p2.y; v[6] = p3.x;
}

__device__ __forceinline__ void pack8(__half* p, const float* v) {
    __half2 q0 = __floats2half2_rn(v[0], v[1]);
    __half2 q1 = __floats2half2_rn(v[2], v[3]);
    __half2 q2 = __floats2half2_rn(v[4], v[5]);
    __half2 q3 = __floats2half2_rn(v[6], 0.f);
    uint4 st;
    st.x = *(unsigned*)&q0; st.y = *(unsigned*)&q1;
    st.z = *(unsigned*)&q2; st.w = *(unsigned*)&q3;
    *((uint4*)p) = st;
}

// accumulate a[0..6] += w * halfrow(hv)
__device__ __forceinline__ void acc7(float* a, float w, uint4 hv) {
    float2 p0 = __half22float2(*(__half2*)&hv.x);
    float2 p1 = __half22float2(*(__half2*)&hv.y);
    float2 p2 = __half22float2(*(__half2*)&hv.z);
    float2 p3 = __half22float2(*(__half2*)&hv.w);
    a[0] = fmaf(w, p0.x, a[0]); a[1] = fmaf(w, p0.y, a[1]);
    a[2] = fmaf(w, p1.x, a[2]); a[3] = fmaf(w, p1.y, a[3]);
    a[4] = fmaf(w, p2.x, a[4]); a[5] = fmaf(w, p2.y, a[5]);
    a[6] = fmaf(w, p3.x, a[6]);
}

__device__ __forceinline__ float wdec(unsigned ed) {
    return __half2float(__ushort_as_half((unsigned short)(ed & 0xffffu)));
}

// ============== gather pass 1: Tx = inv * segsum(w * Xh[src]) ==============
// 8 threads per node: bit2 = dir (out/in), bits0-1 = sub. Inner loop batches
// 4 strided adj entries -> 4 independent 16B gathers in flight (MLP x4).
__global__ __launch_bounds__(256) void gather1_kernel(
    const int* __restrict__ startR, const int* __restrict__ cntR,
    const unsigned* __restrict__ adjR,
    const int* __restrict__ startC, const int* __restrict__ cntC,
    const unsigned* __restrict__ adjC,
    const __half* __restrict__ Xh,
    __half* __restrict__ TxoH, __half* __restrict__ TxiH,
    float* __restrict__ inv_out, float* __restrict__ inv_in)
{
    int tid = blockIdx.x * 256 + threadIdx.x;
    if (tid >= Nn * 8) return;
    int node = tid >> 3;
    int dir = (tid >> 2) & 1, sub = tid & 3;
    const int*      st  = dir ? startC : startR;
    const int*      cn  = dir ? cntC : cntR;
    const unsigned* adj = dir ? adjC : adjR;
    int b = st[node], e = b + cn[node];
    float a[7] = {0.f, 0.f, 0.f, 0.f, 0.f, 0.f, 0.f};
    float sw = 0.f;
    int k = b + sub;
    for (; k + 12 < e; k += 16) {
        unsigned e0 = adj[k], e1 = adj[k + 4], e2 = adj[k + 8], e3 = adj[k + 12];
        uint4 r0 = *(const uint4*)(Xh + (long)(e0 >> 16) * 8);
        uint4 r1 = *(const uint4*)(Xh + (long)(e1 >> 16) * 8);
        uint4 r2 = *(const uint4*)(Xh + (long)(e2 >> 16) * 8);
        uint4 r3 = *(const uint4*)(Xh + (long)(e3 >> 16) * 8);
        float w0 = wdec(e0), w1 = wdec(e1), w2 = wdec(e2), w3 = wdec(e3);
        acc7(a, w0, r0); acc7(a, w1, r1); acc7(a, w2, r2); acc7(a, w3, r3);
        sw += (w0 + w1) + (w2 + w3);
    }
    for (; k < e; k += 4) {
        unsigned ed = adj[k];
        uint4 rv = *(const uint4*)(Xh + (long)(ed >> 16) * 8);
        float w = wdec(ed);
        acc7(a, w, rv);
        sw += w;
    }
    #pragma unroll
    for (int m = 1; m <= 2; m <<= 1) {
        #pragma unroll
        for (int q = 0; q < 7; q++) a[q] += __shfl_xor(a[q], m);
        sw += __shfl_xor(sw, m);
    }
    if (sub == 0) {
        float inv = sw > 0.f ? 1.f / sw : 0.f;
        (dir ? inv_in : inv_out)[node] = inv;
        #pragma unroll
        for (int q = 0; q < 7; q++) a[q] *= inv;
        pack8((dir ? TxiH : TxoH) + (long)node * 8, a);
    }
}

// ====== fused step2: second-order propagation (into LDS, fp32) + dense =====
// Block = 256 threads = 32 nodes.
// Phase A (g2): 8 threads/node (dir = bit2, sub = bits0-1); T2, Tx, X -> f_s.
// Phase B: channel-resident weights (72 VGPR/lane); wave w: channels
// (w&1)*64..+64 for node half (w>>1); pure register FMA inner loop.
__global__ __launch_bounds__(256) void step2_kernel(
    const int* __restrict__ startR, const int* __restrict__ cntR,
    const unsigned* __restrict__ adjR,
    const int* __restrict__ startC, const int* __restrict__ cntC,
    const unsigned* __restrict__ adjC,
    const float* __restrict__ inv_out, const float* __restrict__ inv_in,
    const float* __restrict__ env, const float* __restrict__ night,
    const float* __restrict__ wzT, const float* __restrict__ whT,
    const float* __restrict__ linW, const float* __restrict__ linb,
    __half* __restrict__ Xh,
    const __half* __restrict__ TxoH, const __half* __restrict__ TxiH,
    float* __restrict__ out, int t)
{
    __shared__ float f_s[32][36];
    __shared__ float part_s[2][32];
    int tid = threadIdx.x;
    int base = blockIdx.x * 32;

    // ---- phase A: T2 for this block's 32 nodes, straight into LDS ----
    {
        int nl = tid >> 3;
        int dir = (tid >> 2) & 1, sub = tid & 3;
        int node = base + nl;
        int nc = node < Nn ? node : Nn - 1;   // clamp; output stores guarded
        const int*      st  = dir ? startC : startR;
        const int*      cn  = dir ? cntC : cntR;
        const unsigned* adj = dir ? adjC : adjR;
        const __half*   src = dir ? TxiH : TxoH;
        int b = st[nc], e = b + cn[nc];
        float a[7] = {0.f, 0.f, 0.f, 0.f, 0.f, 0.f, 0.f};
        int k = b + sub;
        for (; k + 12 < e; k += 16) {
            unsigned e0 = adj[k], e1 = adj[k + 4], e2 = adj[k + 8], e3 = adj[k + 12];
            uint4 r0 = *(const uint4*)(src + (long)(e0 >> 16) * 8);
            uint4 r1 = *(const uint4*)(src + (long)(e1 >> 16) * 8);
            uint4 r2 = *(const uint4*)(src + (long)(e2 >> 16) * 8);
            uint4 r3 = *(const uint4*)(src + (long)(e3 >> 16) * 8);
            float w0 = wdec(e0), w1 = wdec(e1), w2 = wdec(e2), w3 = wdec(e3);
            acc7(a, w0, r0); acc7(a, w1, r1); acc7(a, w2, r2); acc7(a, w3, r3);
        }
        for (; k < e; k += 4) {
            unsigned ed = adj[k];
            uint4 rv = *(const uint4*)(src + (long)(ed >> 16) * 8);
            acc7(a, wdec(ed), rv);
        }
        #pragma unroll
        for (int m = 1; m <= 2; m <<= 1) {
            #pragma unroll
            for (int q = 0; q < 7; q++) a[q] += __shfl_xor(a[q], m);
        }
        if (sub == 0) {
            float s2 = 2.f * (dir ? inv_in[nc] : inv_out[nc]);
            float xv[7], tx[7];
            unpack8(Xh + (long)nc * 8, xv);
            unpack8(src + (long)nc * 8, tx);     // own Tx row (dir-matched)
            #pragma unroll
            for (int q = 0; q < 7; q++) {
                f_s[nl][21 + 7 * dir + q] = fmaf(s2, a[q], -xv[q]);
                f_s[nl][7 + 7 * dir + q]  = tx[q];
            }
            if (dir == 0) {
                #pragma unroll
                for (int q = 0; q < 7; q++) f_s[nl][q] = xv[q];
                f_s[nl][35] = 1.f;
            }
        }
    }
    __syncthreads();

    // ---- phase B: dense 36x128x2 contraction + activations + output ----
    int lane = tid & 63;
    int wave = tid >> 6;
    int chSel = wave & 1;
    int ch = chSel * 64 + lane;
    int half_id = wave >> 1;
    float wz[36], wh[36];
    #pragma unroll
    for (int k = 0; k < 36; k++) wz[k] = wzT[k * 128 + ch];
    #pragma unroll
    for (int k = 0; k < 36; k++) wh[k] = whT[k * 128 + ch];
    float lw = linW[ch];
    float lb = linb[0];

    #pragma unroll 1
    for (int n = 0; n < 16; n++) {
        int ni = half_id * 16 + n;
        const float4* fv = (const float4*)f_s[ni];   // broadcast reads
        float hz = 0.f, hh = 0.f;
        #pragma unroll
        for (int q = 0; q < 9; q++) {
            float4 fq = fv[q];
            hz = fmaf(fq.x, wz[q*4+0], hz); hh = fmaf(fq.x, wh[q*4+0], hh);
            hz = fmaf(fq.y, wz[q*4+1], hz); hh = fmaf(fq.y, wh[q*4+1], hh);
            hz = fmaf(fq.z, wz[q*4+2], hz); hh = fmaf(fq.z, wh[q*4+2], hh);
            hz = fmaf(fq.w, wz[q*4+3], hz); hh = fmaf(fq.w, wh[q*4+3], hh);
        }
        float z  = 1.f / (1.f + __expf(-hz));
        float e2 = __expf(2.f * hh);
        float ht = 1.f - 2.f / (e2 + 1.f);           // tanh
        float v = fmaxf((1.f - z) * ht, 0.f) * lw;   // (1-Z)*H~, relu, lin
        v += __shfl_xor(v, 1);  v += __shfl_xor(v, 2);  v += __shfl_xor(v, 4);
        v += __shfl_xor(v, 8);  v += __shfl_xor(v, 16); v += __shfl_xor(v, 32);
        if (lane == 0) part_s[chSel][ni] = v;
    }
    __syncthreads();
    if (tid < 32) {
        int node = base + tid;
        if (node < Nn) {
            float o = part_s[0][tid] + part_s[1][tid] + lb;
            o *= night[(long)node * 13 + t + 1];
            out[(long)node * 13 + t + 1] = o;
            if (t + 1 < Tt) {
                __half* xr = Xh + (long)node * 8;
                xr[0] = __float2half(o);
                #pragma unroll
                for (int c = 0; c < 4; c++)
                    xr[1 + c] = __float2half(env[(long)node * 48 + c * 12 + t + 1]);
            }
        }
    }
}

extern "C" void kernel_launch(void* const* d_in, const int* in_sizes, int n_in,
                              void* d_out, int out_size, void* d_ws, size_t ws_size,
                              hipStream_t stream) {
    const float* x      = (const float*)d_in[0];
    const float* env    = (const float*)d_in[1];
    const float* coords = (const float*)d_in[2];
    const int*   ei     = (const int*)d_in[3];
    const float* ew     = (const float*)d_in[4];
    const float* night  = (const float*)d_in[5];
    const float* Wz     = (const float*)d_in[6];
    const float* bz     = (const float*)d_in[7];
    // d_in[8]=Wr, d_in[9]=br unused (R gate never affects output)
    const float* Wh     = (const float*)d_in[10];
    const float* bh     = (const float*)d_in[11];
    const float* linW   = (const float*)d_in[12];
    const float* linb   = (const float*)d_in[13];
    float* out = (float*)d_out;

    float* w = (float*)d_ws;
    float* wzT     = w;                     // 36*128
    float* whT     = w + 4608;
    float* inv_out = w + 9216;              // N
    float* inv_in  = w + 59216;
    __half* Xh   = (__half*)(w + 109216);   // N x 8 halves (16B-aligned offsets)
    __half* TxoH = (__half*)(w + 309216);
    __half* TxiH = (__half*)(w + 509216);
    int* cntR    = (int*)(w + 709216);      // N
    int* cntC    = cntR + 50000;
    int* startR  = cntC + 50000;            // N
    int* startC  = startR + 50000;
    int* nextR   = startC + 50000;          // N
    int* nextC   = nextR + 50000;
    int* bsum    = nextC + 50000;           // 2 x 256
    int* bbase   = bsum + 512;              // 2 x 256
    int* bandCurR = bbase + 512;            // 8
    int* bandCurC = bandCurR + 8;           // 8
    uint2* packed  = (uint2*)(w + 1010256); // E x 8B (offset even -> 8B aligned)
    unsigned* adjR = (unsigned*)(packed + Ee);   // E x 4B
    unsigned* adjC = adjR + Ee;
    uint2* bucketR = (uint2*)(adjC + Ee);   // E x 8B (two-pass path only)
    uint2* bucketC = bucketR + Ee;          // E x 8B
    // two-pass scatter needs workspace through bucketC end:
    size_t need2 = (size_t)(1010256 + 2 * Ee * 2 /*packed*/ ) * 4
                 + (size_t)Ee * 4 * 2 /*adj*/ + (size_t)Ee * 8 * 2 /*buckets*/;
    bool twopass = ws_size >= need2 + 1024;

    // ---- CSR build (per launch; ws is re-poisoned every call) ----
    hipMemsetAsync(cntR, 0, 2 * Nn * sizeof(int), stream);
    pack_hist_kernel<<<(Ee + 255) / 256, 256, 0, stream>>>(ei, ew, packed, cntR, cntC);
    scanA_kernel<<<dim3(SCB, 2), 256, 0, stream>>>(cntR, cntC, bsum);
    scanB_kernel<<<2, 256, 0, stream>>>(bsum, bbase);
    scanC_kernel<<<dim3(SCB, 2), 256, 0, stream>>>(
        cntR, cntC, bbase, startR, startC, nextR, nextC, bandCurR, bandCurC);
    if (twopass) {
        bucketA_kernel<<<1024, 256, 0, stream>>>(packed, bandCurR, bandCurC,
                                                 bucketR, bucketC);
        scatterB_kernel<<<2048, 256, 0, stream>>>(bucketR, bucketC, startR, startC,
                                                  nextR, nextC, adjR, adjC);
    } else {
        scatter_banded<<<8 * 256, 256, 0, stream>>>(packed, nextR, nextC, adjR, adjC);
    }

    weff_kernel<<<(2 * 36 * 128 + 255) / 256, 256, 0, stream>>>(Wz, Wh, bz, bh, wzT, whT);
    init_kernel<<<(Nn + 255) / 256, 256, 0, stream>>>(x, env, coords, Xh, out);

    for (int t = 0; t < Tt; t++) {
        gather1_kernel<<<(Nn * 8 + 255) / 256, 256, 0, stream>>>(
            startR, cntR, adjR, startC, cntC, adjC, Xh, TxoH, TxiH, inv_out, inv_in);
        step2_kernel<<<(Nn + 31) / 32, 256, 0, stream>>>(
            startR, cntR, adjR, startC, cntC, adjC, inv_out, inv_in,
            env, night, wzT, whT, linW, linb, Xh, TxoH, TxiH, out, t);
    }
}